// Round 4
// baseline (1355.467 us; speedup 1.0000x reference)
//
#include <hip/hip_runtime.h>
#include <hip/hip_bf16.h>

#define SEQ   110
#define HALFS 55
#define EMB   102
#define HEAD  192

typedef short bf16x8 __attribute__((ext_vector_type(8)));
typedef short bf16x4 __attribute__((ext_vector_type(4)));
typedef float f32x4  __attribute__((ext_vector_type(4)));

#define XS    104             // x tile row stride (shorts), 13 granules (odd)
#define QS    200             // q/k row stride, 25 granules (odd)
#define VS    72              // vT row stride, 9 granules (odd)
#define WES   128             // Wt e-stride (padded 102->128)
#define WMAT  (HEAD * WES)
#define XTILE (64 * XS)       // 6656 shorts per half tile

__device__ __forceinline__ short f2bf(float f) {
    unsigned u = __float_as_uint(f);
    unsigned r = u + 0x7fffu + ((u >> 16) & 1u);   // RNE
    return (short)(r >> 16);
}
__device__ __forceinline__ unsigned pk2(float a, float b) {
    return ((unsigned)(unsigned short)f2bf(b) << 16) | (unsigned short)f2bf(a);
}

// Wt[m][h][e] = W_m[e][h] bf16, zero-padded e->128; Wq pre-scaled by 1/sqrt(HEAD).
__global__ void wt_prep(const float* __restrict__ Wq, const float* __restrict__ Wk,
                        const float* __restrict__ Wv, short* __restrict__ wt) {
    int flat = blockIdx.x * 256 + threadIdx.x;
    int m   = flat / WMAT;
    int rem = flat - m * WMAT;
    int h = rem >> 7;
    int e = rem & 127;
    const float* W = (m == 0) ? Wq : (m == 1) ? Wk : Wv;
    float v = (e < EMB) ? W[e * HEAD + h] : 0.0f;
    if (m == 0) v *= 0.07216878364870322f;
    wt[flat] = f2bf(v);
}

// 768 blocks (3/CU, LDS 53.2KB). Block processes batches p = bid + k*gridDim,
// both halves per batch from one x load (register-held, staged twice).
__global__ __launch_bounds__(256, 3)
void attn_head(const float* __restrict__ x, const short* __restrict__ wt,
               float* __restrict__ out, int B) {
    const int tid  = threadIdx.x;
    const int w    = tid >> 6;
    const int lane = tid & 63;
    const int g    = lane >> 4;
    const int r    = lane & 15;

    __shared__ __attribute__((aligned(16))) short u1[HEAD * VS];   // 27648 B: x tiles -> vT
    __shared__ __attribute__((aligned(16))) short qk[64 * QS];     // 25600 B: q -> k

    // ---- weight fragments (unit-invariant; compiler balances regs vs L2 reloads) ----
    const short* wtq = wt;
    const short* wtk = wt + WMAT;
    const short* wtv = wt + 2 * WMAT;
    bf16x8 wqf[3][4], wkf[3][4], wvf[3][4];
    #pragma unroll
    for (int mi = 0; mi < 3; ++mi) {
        const int hrow = 16 * (w + 4 * mi) + r;
        #pragma unroll
        for (int kk = 0; kk < 4; ++kk) {
            wqf[mi][kk] = *(const bf16x8*)(wtq + hrow * WES + 32 * kk + 8 * g);
            wkf[mi][kk] = *(const bf16x8*)(wtk + hrow * WES + 32 * kk + 8 * g);
            wvf[mi][kk] = *(const bf16x8*)(wtv + hrow * WES + 32 * kk + 8 * g);
        }
    }

    // ---- staging LDS offsets: ba(15b) | bb(15b)<<16 | cross<<31 ----
    unsigned soff[11];
    #pragma unroll
    for (int it = 0; it < 11; ++it) {
        int i4 = tid + it * 256;
        if (i4 < 2805) {
            int fc  = i4 * 4;
            int row = (int)(((unsigned long long)fc * 41121ull) >> 22);  // /102
            int e   = fc - row * EMB;
            int tile = row >= HALFS;
            int lr   = row - HALFS * tile;
            int cross = (e == 100);
            int rowb  = row + cross;
            int tileb = rowb >= HALFS;
            int lrb   = rowb - HALFS * tileb;
            int ba = tile * XTILE + lr * XS + e;
            int bb = cross ? (tileb * XTILE + lrb * XS) : (ba + 2);
            soff[it] = (unsigned)ba | ((unsigned)bb << 16) | ((unsigned)cross << 31);
        } else soff[it] = 0xFFFFFFFFu;
    }

    const int stride = (int)gridDim.x;
    unsigned xv0[11], xv1[11];
    {   // prefetch first batch
        const float4* xb4 = (const float4*)(x + (size_t)blockIdx.x * (SEQ * EMB));
        #pragma unroll
        for (int it = 0; it < 11; ++it) {
            int i4 = tid + it * 256;
            if (i4 < 2805) { float4 v = xb4[i4]; xv0[it] = pk2(v.x, v.y); xv1[it] = pk2(v.z, v.w); }
        }
    }

    for (int p = blockIdx.x; p < B; p += stride) {
        #pragma unroll 1
        for (int half = 0; half < 2; ++half) {
            // ---- stage: pad zeros + x b64 stores from registers ----
            {
                unsigned long long* z = (unsigned long long*)u1;
                #pragma unroll
                for (int i0 = 0; i0 < 2; ++i0) {
                    int ii = tid + i0 * 256;
                    if (ii < 468) z[(ii < 234 ? 1430 : 2860) + ii] = 0ull;
                }
                if (tid < 110)
                    *(unsigned*)(u1 + (tid & 1) * XTILE + (tid >> 1) * XS + 102) = 0u;
                #pragma unroll
                for (int it = 0; it < 11; ++it) {
                    unsigned so = soff[it];
                    if (so != 0xFFFFFFFFu) {
                        int ba = (int)(so & 0x7FFFu);
                        if (so & 0x80000000u) {
                            *(unsigned*)(u1 + ba) = xv0[it];
                            *(unsigned*)(u1 + ((so >> 16) & 0x7FFFu)) = xv1[it];
                        } else {
                            uint2 t2; t2.x = xv0[it]; t2.y = xv1[it];
                            *(uint2*)(u1 + ba) = t2;
                        }
                    }
                }
            }
            __syncthreads();   // barA: x visible

            // prefetch next batch during second half (xv fully consumed)
            if (half == 1) {
                int pn = p + stride;
                if (pn < B) {
                    const float4* xb4 = (const float4*)(x + (size_t)pn * (SEQ * EMB));
                    #pragma unroll
                    for (int it = 0; it < 11; ++it) {
                        int i4 = tid + it * 256;
                        if (i4 < 2805) { float4 v = xb4[i4]; xv0[it] = pk2(v.x, v.y); xv1[it] = pk2(v.z, v.w); }
                    }
                }
            }

            const short* x_own = u1 + half * XTILE;
            const short* x_oth = u1 + (half ^ 1) * XTILE;

            // ---- q-GEMM -> qk ----
            #pragma unroll
            for (int st = 0; st < 4; ++st) {
                const short* bo = x_own + (16 * st + r) * XS;
                bf16x8 bx[4];
                #pragma unroll
                for (int kk = 0; kk < 3; ++kk) bx[kk] = *(const bf16x8*)(bo + 32 * kk + 8 * g);
                bf16x8 zz = {};
                bx[3] = zz;
                if (g == 0) bx[3] = *(const bf16x8*)(bo + 96);
                #pragma unroll
                for (int mi = 0; mi < 3; ++mi) {
                    f32x4 acc = {0.f, 0.f, 0.f, 0.f};
                    #pragma unroll
                    for (int kk = 0; kk < 4; ++kk)
                        acc = __builtin_amdgcn_mfma_f32_16x16x32_bf16(wqf[mi][kk], bx[kk], acc, 0, 0, 0);
                    uint2 t2; t2.x = pk2(acc[0], acc[1]); t2.y = pk2(acc[2], acc[3]);
                    *(uint2*)(&qk[(16 * st + r) * QS + 16 * (w + 4 * mi) + 4 * g]) = t2;
                }
            }
            __syncthreads();   // barB: q visible

            // ---- k/v-GEMM to registers (x_oth reads; qk untouched) ----
            unsigned kpk[4][3][2], vpk[4][3][2];
            #pragma unroll
            for (int st = 0; st < 4; ++st) {
                const short* bt = x_oth + (16 * st + r) * XS;
                bf16x8 bx[4];
                #pragma unroll
                for (int kk = 0; kk < 3; ++kk) bx[kk] = *(const bf16x8*)(bt + 32 * kk + 8 * g);
                bf16x8 zz = {};
                bx[3] = zz;
                if (g == 0) bx[3] = *(const bf16x8*)(bt + 96);
                #pragma unroll
                for (int mi = 0; mi < 3; ++mi) {
                    f32x4 acc = {0.f, 0.f, 0.f, 0.f};
                    #pragma unroll
                    for (int kk = 0; kk < 4; ++kk)
                        acc = __builtin_amdgcn_mfma_f32_16x16x32_bf16(wkf[mi][kk], bx[kk], acc, 0, 0, 0);
                    kpk[st][mi][0] = pk2(acc[0], acc[1]);
                    kpk[st][mi][1] = pk2(acc[2], acc[3]);
                }
                #pragma unroll
                for (int mi = 0; mi < 3; ++mi) {
                    f32x4 acc = {0.f, 0.f, 0.f, 0.f};
                    #pragma unroll
                    for (int kk = 0; kk < 4; ++kk)
                        acc = __builtin_amdgcn_mfma_f32_16x16x32_bf16(bx[kk], wvf[mi][kk], acc, 0, 0, 0);
                    vpk[st][mi][0] = pk2(acc[0], acc[1]);
                    vpk[st][mi][1] = pk2(acc[2], acc[3]);
                }
            }

            // ---- read q B-frags (after barB; q region still intact) ----
            bf16x8 bq[6];
            {
                const short* qb = &qk[(16 * w + r) * QS + 8 * g];
                #pragma unroll
                for (int kk = 0; kk < 6; ++kk) bq[kk] = *(const bf16x8*)(qb + 32 * kk);
            }
            __syncthreads();   // barC: all bq reads + x reads done

            // ---- write k over q; vT over x ----
            #pragma unroll
            for (int st = 0; st < 4; ++st) {
                #pragma unroll
                for (int mi = 0; mi < 3; ++mi) {
                    uint2 t2; t2.x = kpk[st][mi][0]; t2.y = kpk[st][mi][1];
                    *(uint2*)(&qk[(16 * st + r) * QS + 16 * (w + 4 * mi) + 4 * g]) = t2;
                    uint2 v2; v2.x = vpk[st][mi][0]; v2.y = vpk[st][mi][1];
                    *(uint2*)(&u1[(16 * (w + 4 * mi) + r) * VS + 16 * st + 4 * g]) = v2;
                }
            }
            __syncthreads();   // barD: k + vT visible

            // ---- scoresT = k @ qT (wave's 16 queries s = 16w+r) ----
            float sc[4][4];
            #pragma unroll
            for (int mt = 0; mt < 4; ++mt) {
                const short* kb = &qk[(16 * mt + r) * QS + 8 * g];
                f32x4 acc = {0.f, 0.f, 0.f, 0.f};
                #pragma unroll
                for (int kk = 0; kk < 6; ++kk)
                    acc = __builtin_amdgcn_mfma_f32_16x16x32_bf16(
                        *(const bf16x8*)(kb + 32 * kk), bq[kk], acc, 0, 0, 0);
                #pragma unroll
                for (int j = 0; j < 4; ++j) sc[mt][j] = acc[j];
            }
            #pragma unroll
            for (int j = 0; j < 4; ++j)
                if (48 + 4 * g + j >= HALFS) sc[3][j] = -1e30f;

            float mx = -1e30f;
            #pragma unroll
            for (int mt = 0; mt < 4; ++mt) {
                #pragma unroll
                for (int j = 0; j < 4; ++j) mx = fmaxf(mx, sc[mt][j]);
            }
            mx = fmaxf(mx, __shfl_xor(mx, 16));
            mx = fmaxf(mx, __shfl_xor(mx, 32));
            float pr[4][4];
            float sum = 0.f;
            #pragma unroll
            for (int mt = 0; mt < 4; ++mt) {
                #pragma unroll
                for (int j = 0; j < 4; ++j) { pr[mt][j] = __expf(sc[mt][j] - mx); sum += pr[mt][j]; }
            }
            sum += __shfl_xor(sum, 16);
            sum += __shfl_xor(sum, 32);
            float rs = 1.0f / sum;

            // ---- P packed in regs: pu[mt][q] = bf16{t=16mt+4g+2q, +1} for s=16w+r ----
            unsigned pu[4][2];
            #pragma unroll
            for (int mt = 0; mt < 4; ++mt) {
                pu[mt][0] = pk2(pr[mt][0] * rs, pr[mt][1] * rs);
                pu[mt][1] = pk2(pr[mt][2] * rs, pr[mt][3] * rs);
            }

            // ---- register-only P exchange -> PV B-frags (16 shfl + selects) ----
            // consumer (g,r): bp0 = P[s=16w+r][t=8g..8g+7], bp1 = +32.
            // sources: lanes 32*(g&1)+r and +16; select mt by g>>1.
            const int src0 = ((g & 1) << 5) + r;
            const int src1 = src0 + 16;
            const bool hi = (g >> 1) != 0;
            unsigned A00 = (unsigned)__shfl((int)pu[0][0], src0), A01 = (unsigned)__shfl((int)pu[0][1], src0);
            unsigned A02 = (unsigned)__shfl((int)pu[0][0], src1), A03 = (unsigned)__shfl((int)pu[0][1], src1);
            unsigned B00 = (unsigned)__shfl((int)pu[1][0], src0), B01 = (unsigned)__shfl((int)pu[1][1], src0);
            unsigned B02 = (unsigned)__shfl((int)pu[1][0], src1), B03 = (unsigned)__shfl((int)pu[1][1], src1);
            unsigned C00 = (unsigned)__shfl((int)pu[2][0], src0), C01 = (unsigned)__shfl((int)pu[2][1], src0);
            unsigned C02 = (unsigned)__shfl((int)pu[2][0], src1), C03 = (unsigned)__shfl((int)pu[2][1], src1);
            unsigned D00 = (unsigned)__shfl((int)pu[3][0], src0), D01 = (unsigned)__shfl((int)pu[3][1], src0);
            unsigned D02 = (unsigned)__shfl((int)pu[3][0], src1), D03 = (unsigned)__shfl((int)pu[3][1], src1);
            uint4 q0, q1;
            q0.x = hi ? B00 : A00; q0.y = hi ? B01 : A01; q0.z = hi ? B02 : A02; q0.w = hi ? B03 : A03;
            q1.x = hi ? D00 : C00; q1.y = hi ? D01 : C01; q1.z = hi ? D02 : C02; q1.w = hi ? D03 : C03;
            bf16x8 bp0, bp1;
            __builtin_memcpy(&bp0, &q0, 16);
            __builtin_memcpy(&bp1, &q1, 16);

            // ---- PV: outT = vT @ PT ----
            const int srow  = 16 * w + r;
            const bool valid = srow < HALFS;
            float* orow = out + (size_t)p * (SEQ * HEAD) + (size_t)(half * HALFS + srow) * HEAD;
            #pragma unroll
            for (int mt = 0; mt < 12; ++mt) {
                const short* vb = &u1[(16 * mt + r) * VS + 8 * g];
                f32x4 acc = {0.f, 0.f, 0.f, 0.f};
                acc = __builtin_amdgcn_mfma_f32_16x16x32_bf16(*(const bf16x8*)(vb),      bp0, acc, 0, 0, 0);
                acc = __builtin_amdgcn_mfma_f32_16x16x32_bf16(*(const bf16x8*)(vb + 32), bp1, acc, 0, 0, 0);
                if (valid) {
                    float4 st; st.x = acc[0]; st.y = acc[1]; st.z = acc[2]; st.w = acc[3];
                    *(float4*)(orow + 16 * mt + 4 * g) = st;
                }
            }
            __syncthreads();   // barE: vT + k reads done before next staging
        }
    }
}

extern "C" void kernel_launch(void* const* d_in, const int* in_sizes, int n_in,
                              void* d_out, int out_size, void* d_ws, size_t ws_size,
                              hipStream_t stream) {
    const float* x  = (const float*)d_in[0];
    const float* Wq = (const float*)d_in[1];
    const float* Wk = (const float*)d_in[2];
    const float* Wv = (const float*)d_in[3];
    short* wt = (short*)d_ws;                       // 3*192*128*2 = 147456 B
    int B = in_sizes[0] / (SEQ * EMB);              // 8192
    wt_prep<<<(3 * WMAT) / 256, 256, 0, stream>>>(Wq, Wk, Wv, wt);
    attn_head<<<768, 256, 0, stream>>>(x, wt, (float*)d_out, B);
}

// Round 5
// 514.374 us; speedup vs baseline: 2.6352x; 2.6352x over previous
//
#include <hip/hip_runtime.h>
#include <hip/hip_bf16.h>

#define SEQ   110
#define HALFS 55
#define EMB   102
#define HEAD  192

typedef short bf16x8 __attribute__((ext_vector_type(8)));
typedef float f32x4  __attribute__((ext_vector_type(4)));

#define XS    104             // x tile row stride (shorts)
#define QS    200             // q/k row stride (400 B = 25 granules, 16B-aligned rows)
#define VS    72              // vT row stride (144 B = 9 granules, 16B-aligned rows)
#define WES   128             // Wt e-stride (padded 102->128)
#define WMAT  (HEAD * WES)
#define XTILE (64 * XS)       // 6656 shorts per half tile

__device__ __forceinline__ short f2bf(float f) {
    unsigned u = __float_as_uint(f);
    unsigned r = u + 0x7fffu + ((u >> 16) & 1u);   // RNE
    return (short)(r >> 16);
}
__device__ __forceinline__ unsigned pk2(float a, float b) {
    return ((unsigned)(unsigned short)f2bf(b) << 16) | (unsigned short)f2bf(a);
}

// Wt[m][h][e] = W_m[e][h] bf16, zero-padded e->128; Wq pre-scaled by 1/sqrt(HEAD).
__global__ void wt_prep(const float* __restrict__ Wq, const float* __restrict__ Wk,
                        const float* __restrict__ Wv, short* __restrict__ wt) {
    int flat = blockIdx.x * 256 + threadIdx.x;
    int m   = flat / WMAT;
    int rem = flat - m * WMAT;
    int h = rem >> 7;
    int e = rem & 127;
    const float* W = (m == 0) ? Wq : (m == 1) ? Wk : Wv;
    float v = (e < EMB) ? W[e * HEAD + h] : 0.0f;
    if (m == 0) v *= 0.07216878364870322f;
    wt[flat] = f2bf(v);
}

// 512 persistent blocks (2/CU). Per batch: x staged ONCE (persistent region),
// weights pinned in 144 VGPRs, k->LDS directly, vT overlays dead q.
__global__ __launch_bounds__(256, 2)
void attn_head(const float* __restrict__ x, const short* __restrict__ wt,
               float* __restrict__ out, int B) {
    const int tid  = threadIdx.x;
    const int w    = tid >> 6;
    const int lane = tid & 63;
    const int g    = lane >> 4;
    const int r    = lane & 15;

    __shared__ __attribute__((aligned(16))) short ux[2 * XTILE];   // 26624 B: x, persistent per batch
    __shared__ __attribute__((aligned(16))) short r1[192 * VS];    // 27648 B: q (64xQS) -> vT (192xVS)
    __shared__ __attribute__((aligned(16))) short r2[64 * QS];     // 25600 B: k

    // ---- load weight fragments once; PIN in VGPRs (prevents L2 remat / per-use reload) ----
    bf16x8 wqf[3][4], wkf[3][4], wvf[3][4];
    {
        const short* wtq = wt;
        const short* wtk = wt + WMAT;
        const short* wtv = wt + 2 * WMAT;
        #pragma unroll
        for (int mi = 0; mi < 3; ++mi) {
            const int hrow = 16 * (w + 4 * mi) + r;
            #pragma unroll
            for (int kk = 0; kk < 4; ++kk) {
                wqf[mi][kk] = *(const bf16x8*)(wtq + hrow * WES + 32 * kk + 8 * g);
                wkf[mi][kk] = *(const bf16x8*)(wtk + hrow * WES + 32 * kk + 8 * g);
                wvf[mi][kk] = *(const bf16x8*)(wtv + hrow * WES + 32 * kk + 8 * g);
            }
        }
        #pragma unroll
        for (int mi = 0; mi < 3; ++mi) {
            #pragma unroll
            for (int kk = 0; kk < 4; ++kk) {
                asm volatile("" : "+v"(wqf[mi][kk]));
                asm volatile("" : "+v"(wkf[mi][kk]));
                asm volatile("" : "+v"(wvf[mi][kk]));
            }
        }
    }

    // ---- staging LDS offsets: ba(15b) | bb(15b)<<16 | cross<<31 ----
    unsigned soff[11];
    #pragma unroll
    for (int it = 0; it < 11; ++it) {
        int i4 = tid + it * 256;
        if (i4 < 2805) {
            int fc  = i4 * 4;
            int row = (int)(((unsigned long long)fc * 41121ull) >> 22);  // /102
            int e   = fc - row * EMB;
            int tile = row >= HALFS;
            int lr   = row - HALFS * tile;
            int cross = (e == 100);
            int rowb  = row + cross;
            int tileb = rowb >= HALFS;
            int lrb   = rowb - HALFS * tileb;
            int ba = tile * XTILE + lr * XS + e;
            int bb = cross ? (tileb * XTILE + lrb * XS) : (ba + 2);
            soff[it] = (unsigned)ba | ((unsigned)bb << 16) | ((unsigned)cross << 31);
        } else soff[it] = 0xFFFFFFFFu;
    }

    // ---- one-time pad zeroing (staging never touches rows>=55 or cols 102/103) ----
    {
        unsigned long long* z = (unsigned long long*)ux;
        #pragma unroll
        for (int i0 = 0; i0 < 2; ++i0) {
            int ii = tid + i0 * 256;
            if (ii < 468) z[(ii < 234 ? 1430 : 2860) + ii] = 0ull;   // rows 55..63 both tiles
        }
        if (tid < 110)
            *(unsigned*)(ux + (tid & 1) * XTILE + (tid >> 1) * XS + 102) = 0u;
    }

    const int stride = (int)gridDim.x;
    unsigned xv0[11], xv1[11];

    auto loadx = [&](int batch) {
        const float4* xb4 = (const float4*)(x + (size_t)batch * (SEQ * EMB));
        #pragma unroll
        for (int it = 0; it < 11; ++it) {
            int i4 = tid + it * 256;
            if (i4 < 2805) { float4 v = xb4[i4]; xv0[it] = pk2(v.x, v.y); xv1[it] = pk2(v.z, v.w); }
        }
    };
    auto stagex = [&]() {
        #pragma unroll
        for (int it = 0; it < 11; ++it) {
            unsigned so = soff[it];
            if (so != 0xFFFFFFFFu) {
                int ba = (int)(so & 0x7FFFu);
                if (so & 0x80000000u) {
                    *(unsigned*)(ux + ba) = xv0[it];
                    *(unsigned*)(ux + ((so >> 16) & 0x7FFFu)) = xv1[it];
                } else {
                    uint2 t2; t2.x = xv0[it]; t2.y = xv1[it];
                    *(uint2*)(ux + ba) = t2;
                }
            }
        }
    };

    loadx(blockIdx.x);
    stagex();
    __syncthreads();   // initial: zeros + x visible

    for (int p = blockIdx.x; p < B; p += stride) {
        #pragma unroll 1
        for (int half = 0; half < 2; ++half) {
            const short* x_own = ux + half * XTILE;
            const short* x_oth = ux + (half ^ 1) * XTILE;

            // ---- q-GEMM -> r1 ----
            #pragma unroll
            for (int st = 0; st < 4; ++st) {
                const short* bo = x_own + (16 * st + r) * XS;
                bf16x8 bx[4];
                #pragma unroll
                for (int kk = 0; kk < 3; ++kk) bx[kk] = *(const bf16x8*)(bo + 32 * kk + 8 * g);
                bf16x8 zz = {};
                bx[3] = zz;
                if (g == 0) bx[3] = *(const bf16x8*)(bo + 96);
                #pragma unroll
                for (int mi = 0; mi < 3; ++mi) {
                    f32x4 acc = {0.f, 0.f, 0.f, 0.f};
                    #pragma unroll
                    for (int kk = 0; kk < 4; ++kk)
                        acc = __builtin_amdgcn_mfma_f32_16x16x32_bf16(wqf[mi][kk], bx[kk], acc, 0, 0, 0);
                    uint2 t2; t2.x = pk2(acc[0], acc[1]); t2.y = pk2(acc[2], acc[3]);
                    *(uint2*)(&r1[(16 * st + r) * QS + 16 * (w + 4 * mi) + 4 * g]) = t2;
                }
            }
            // ---- k-GEMM -> r2 ----
            #pragma unroll
            for (int st = 0; st < 4; ++st) {
                const short* bt = x_oth + (16 * st + r) * XS;
                bf16x8 bx[4];
                #pragma unroll
                for (int kk = 0; kk < 3; ++kk) bx[kk] = *(const bf16x8*)(bt + 32 * kk + 8 * g);
                bf16x8 zz = {};
                bx[3] = zz;
                if (g == 0) bx[3] = *(const bf16x8*)(bt + 96);
                #pragma unroll
                for (int mi = 0; mi < 3; ++mi) {
                    f32x4 acc = {0.f, 0.f, 0.f, 0.f};
                    #pragma unroll
                    for (int kk = 0; kk < 4; ++kk)
                        acc = __builtin_amdgcn_mfma_f32_16x16x32_bf16(wkf[mi][kk], bx[kk], acc, 0, 0, 0);
                    uint2 t2; t2.x = pk2(acc[0], acc[1]); t2.y = pk2(acc[2], acc[3]);
                    *(uint2*)(&r2[(16 * st + r) * QS + 16 * (w + 4 * mi) + 4 * g]) = t2;
                }
            }
            __syncthreads();   // barB: q + k visible

            // ---- scoresT = k @ qT (wave's queries s = 16w+r) ----
            bf16x8 bq[6];
            {
                const short* qb = &r1[(16 * w + r) * QS + 8 * g];
                #pragma unroll
                for (int kk = 0; kk < 6; ++kk) bq[kk] = *(const bf16x8*)(qb + 32 * kk);
            }
            float sc[4][4];
            #pragma unroll
            for (int mt = 0; mt < 4; ++mt) {
                const short* kb = &r2[(16 * mt + r) * QS + 8 * g];
                f32x4 acc = {0.f, 0.f, 0.f, 0.f};
                #pragma unroll
                for (int kk = 0; kk < 6; ++kk)
                    acc = __builtin_amdgcn_mfma_f32_16x16x32_bf16(
                        *(const bf16x8*)(kb + 32 * kk), bq[kk], acc, 0, 0, 0);
                #pragma unroll
                for (int j = 0; j < 4; ++j) sc[mt][j] = acc[j];
            }
            #pragma unroll
            for (int j = 0; j < 4; ++j)
                if (48 + 4 * g + j >= HALFS) sc[3][j] = -1e30f;

            float mx = -1e30f;
            #pragma unroll
            for (int mt = 0; mt < 4; ++mt) {
                #pragma unroll
                for (int j = 0; j < 4; ++j) mx = fmaxf(mx, sc[mt][j]);
            }
            mx = fmaxf(mx, __shfl_xor(mx, 16));
            mx = fmaxf(mx, __shfl_xor(mx, 32));
            float pr[4][4];
            float sum = 0.f;
            #pragma unroll
            for (int mt = 0; mt < 4; ++mt) {
                #pragma unroll
                for (int j = 0; j < 4; ++j) { pr[mt][j] = __expf(sc[mt][j] - mx); sum += pr[mt][j]; }
            }
            sum += __shfl_xor(sum, 16);
            sum += __shfl_xor(sum, 32);
            float rs = 1.0f / sum;

            unsigned pu[4][2];
            #pragma unroll
            for (int mt = 0; mt < 4; ++mt) {
                pu[mt][0] = pk2(pr[mt][0] * rs, pr[mt][1] * rs);
                pu[mt][1] = pk2(pr[mt][2] * rs, pr[mt][3] * rs);
            }

            // ---- register-only P exchange -> PV B-frags ----
            const int src0 = ((g & 1) << 5) + r;
            const int src1 = src0 + 16;
            const bool hi = (g >> 1) != 0;
            unsigned A00 = (unsigned)__shfl((int)pu[0][0], src0), A01 = (unsigned)__shfl((int)pu[0][1], src0);
            unsigned A02 = (unsigned)__shfl((int)pu[0][0], src1), A03 = (unsigned)__shfl((int)pu[0][1], src1);
            unsigned B00 = (unsigned)__shfl((int)pu[1][0], src0), B01 = (unsigned)__shfl((int)pu[1][1], src0);
            unsigned B02 = (unsigned)__shfl((int)pu[1][0], src1), B03 = (unsigned)__shfl((int)pu[1][1], src1);
            unsigned C00 = (unsigned)__shfl((int)pu[2][0], src0), C01 = (unsigned)__shfl((int)pu[2][1], src0);
            unsigned C02 = (unsigned)__shfl((int)pu[2][0], src1), C03 = (unsigned)__shfl((int)pu[2][1], src1);
            unsigned D00 = (unsigned)__shfl((int)pu[3][0], src0), D01 = (unsigned)__shfl((int)pu[3][1], src0);
            unsigned D02 = (unsigned)__shfl((int)pu[3][0], src1), D03 = (unsigned)__shfl((int)pu[3][1], src1);
            uint4 q0, q1;
            q0.x = hi ? B00 : A00; q0.y = hi ? B01 : A01; q0.z = hi ? B02 : A02; q0.w = hi ? B03 : A03;
            q1.x = hi ? D00 : C00; q1.y = hi ? D01 : C01; q1.z = hi ? D02 : C02; q1.w = hi ? D03 : C03;
            bf16x8 bp0, bp1;
            __builtin_memcpy(&bp0, &q0, 16);
            __builtin_memcpy(&bp1, &q1, 16);

            __syncthreads();   // barC: all q/k reads done -> r1 reusable for vT

            // ---- v-GEMM -> vT into r1 (transient C-frags, immediate write) ----
            #pragma unroll
            for (int st = 0; st < 4; ++st) {
                const short* bt = x_oth + (16 * st + r) * XS;
                bf16x8 bx[4];
                #pragma unroll
                for (int kk = 0; kk < 3; ++kk) bx[kk] = *(const bf16x8*)(bt + 32 * kk + 8 * g);
                bf16x8 zz = {};
                bx[3] = zz;
                if (g == 0) bx[3] = *(const bf16x8*)(bt + 96);
                #pragma unroll
                for (int mi = 0; mi < 3; ++mi) {
                    f32x4 acc = {0.f, 0.f, 0.f, 0.f};
                    #pragma unroll
                    for (int kk = 0; kk < 4; ++kk)
                        acc = __builtin_amdgcn_mfma_f32_16x16x32_bf16(bx[kk], wvf[mi][kk], acc, 0, 0, 0);
                    uint2 t2; t2.x = pk2(acc[0], acc[1]); t2.y = pk2(acc[2], acc[3]);
                    *(uint2*)(&r1[(16 * (w + 4 * mi) + r) * VS + 16 * st + 4 * g]) = t2;
                }
            }
            __syncthreads();   // barD: vT visible

            // ---- PV + output; prefetch issue (half0) / next-batch stage (half1) hidden here ----
            const int srow  = 16 * w + r;
            const bool valid = srow < HALFS;
            float* orow = out + (size_t)p * (SEQ * HEAD) + (size_t)(half * HALFS + srow) * HEAD;
            #pragma unroll
            for (int mt = 0; mt < 12; ++mt) {
                const short* vb = &r1[(16 * mt + r) * VS + 8 * g];
                f32x4 acc = {0.f, 0.f, 0.f, 0.f};
                acc = __builtin_amdgcn_mfma_f32_16x16x32_bf16(*(const bf16x8*)(vb),      bp0, acc, 0, 0, 0);
                acc = __builtin_amdgcn_mfma_f32_16x16x32_bf16(*(const bf16x8*)(vb + 32), bp1, acc, 0, 0, 0);
                if (valid) {
                    float4 st4; st4.x = acc[0]; st4.y = acc[1]; st4.z = acc[2]; st4.w = acc[3];
                    *(float4*)(orow + 16 * mt + 4 * g) = st4;
                }
            }
            if (half == 0) {
                int pn = p + stride;
                if (pn < B) loadx(pn);          // issue global loads; latency spans half1
            } else {
                int pn = p + stride;
                if (pn < B) stagex();           // ux writes; PV reads r1 only -> no conflict
            }
            __syncthreads();   // barE: PV reads + (stage) done before next q/k writes
        }
    }
}

extern "C" void kernel_launch(void* const* d_in, const int* in_sizes, int n_in,
                              void* d_out, int out_size, void* d_ws, size_t ws_size,
                              hipStream_t stream) {
    const float* x  = (const float*)d_in[0];
    const float* Wq = (const float*)d_in[1];
    const float* Wk = (const float*)d_in[2];
    const float* Wv = (const float*)d_in[3];
    short* wt = (short*)d_ws;                       // 3*192*128*2 = 147456 B
    int B = in_sizes[0] / (SEQ * EMB);              // 8192
    wt_prep<<<(3 * WMAT) / 256, 256, 0, stream>>>(Wq, Wk, Wv, wt);
    attn_head<<<512, 256, 0, stream>>>(x, wt, (float*)d_out, B);
}

// Round 6
// 372.240 us; speedup vs baseline: 3.6414x; 1.3818x over previous
//
#include <hip/hip_runtime.h>
#include <hip/hip_bf16.h>

#define SEQ   110
#define HALFS 55
#define EMB   102
#define HEAD  192

typedef short bf16x8 __attribute__((ext_vector_type(8)));
typedef float f32x4  __attribute__((ext_vector_type(4)));

#define XS    104               // x/y tile row stride (shorts), 13 granules (odd)
#define XTILE (64 * XS)         // 6656 shorts per half tile
#define MTS   128               // Mt row stride (shorts)
#define MTROWS 112
#define MT_SHORTS (MTROWS * MTS)   // 14336
#define WES   128               // WvT e-stride

__device__ __forceinline__ short f2bf(float f) {
    unsigned u = __float_as_uint(f);
    unsigned r = u + 0x7fffu + ((u >> 16) & 1u);   // RNE
    return (short)(r >> 16);
}
__device__ __forceinline__ unsigned pk2(float a, float b) {
    return ((unsigned)(unsigned short)f2bf(b) << 16) | (unsigned short)f2bf(a);
}

// ws layout: [ Mt : 112x128 bf16 ][ WvT : 192x128 bf16 ]
// Mt[i][j] = scale * sum_h Wq[j][h] * Wk[i][h]   (i = e_out, j = e_in), zero-padded.
// WvT[h][e] = Wv[e][h], zero-padded.
__global__ void prep(const float* __restrict__ Wq, const float* __restrict__ Wk,
                     const float* __restrict__ Wv, short* __restrict__ ws) {
    int flat = blockIdx.x * 256 + threadIdx.x;
    if (flat < MT_SHORTS) {
        int i = flat >> 7, j = flat & 127;
        float v = 0.0f;
        if (i < EMB && j < EMB) {
            const float4* q4 = (const float4*)(Wq + j * HEAD);
            const float4* k4 = (const float4*)(Wk + i * HEAD);
            float s = 0.0f;
            #pragma unroll 4
            for (int h4 = 0; h4 < HEAD / 4; ++h4) {
                float4 a = q4[h4], b = k4[h4];
                s += a.x * b.x + a.y * b.y + a.z * b.z + a.w * b.w;
            }
            v = s * 0.07216878364870322f;   // 1/sqrt(192)
        }
        ws[flat] = f2bf(v);
    } else if (flat < MT_SHORTS + HEAD * WES) {
        int idx = flat - MT_SHORTS;
        int h = idx >> 7, e = idx & 127;
        float v = (e < EMB) ? Wv[e * HEAD + h] : 0.0f;
        ws[flat] = f2bf(v);
    }
}

// 512 persistent blocks. Per batch: stage x (both halves) once, y = x@G once,
// then both halves run with ZERO LDS writes / ZERO barriers (all-register P and v
// redistribution via intra-wave shuffles). 3 barriers per batch.
__global__ __launch_bounds__(256, 2)
void attn_head(const float* __restrict__ x, const short* __restrict__ ws,
               float* __restrict__ out, int B) {
    const int tid  = threadIdx.x;
    const int w    = tid >> 6;
    const int lane = tid & 63;
    const int g    = lane >> 4;
    const int r    = lane & 15;

    __shared__ __attribute__((aligned(16))) short ux[2 * XTILE];   // 26624 B
    __shared__ __attribute__((aligned(16))) short uy[2 * XTILE];   // 26624 B

    const short* Mt  = ws;
    const short* WvT = ws + MT_SHORTS;

    // ---- Wv fragments (loop-invariant; 48 VGPR or remat from L2 at compiler's choice) ----
    bf16x8 wvf[3][4];
    #pragma unroll
    for (int mi = 0; mi < 3; ++mi) {
        const int hrow = 16 * (w + 4 * mi) + r;
        #pragma unroll
        for (int kk = 0; kk < 4; ++kk)
            wvf[mi][kk] = *(const bf16x8*)(WvT + hrow * WES + 32 * kk + 8 * g);
    }

    // ---- one-time pad zeroing of ux (rows 55..63 both tiles; cols 102/103 rows 0..54) ----
    {
        unsigned long long* z = (unsigned long long*)ux;
        #pragma unroll
        for (int i0 = 0; i0 < 2; ++i0) {
            int ii = tid + i0 * 256;
            if (ii < 468) z[(ii < 234 ? 1430 : 2860) + ii] = 0ull;
        }
        if (tid < 110)
            *(unsigned*)(ux + (tid & 1) * XTILE + (tid >> 1) * XS + 102) = 0u;
    }

    unsigned xv0[11], xv1[11];
    auto loadx = [&](int batch) {
        const float4* xb4 = (const float4*)(x + (size_t)batch * (SEQ * EMB));
        #pragma unroll
        for (int it = 0; it < 11; ++it) {
            int i4 = tid + it * 256;
            if (i4 < 2805) { float4 v = xb4[i4]; xv0[it] = pk2(v.x, v.y); xv1[it] = pk2(v.z, v.w); }
        }
    };
    auto stagex = [&]() {
        #pragma unroll
        for (int it = 0; it < 11; ++it) {
            int i4 = tid + it * 256;
            if (i4 < 2805) {
                int fc  = i4 * 4;
                int row = (int)(((unsigned long long)fc * 41121ull) >> 22);  // /102
                int e   = fc - row * EMB;
                int tile = row >= HALFS;
                int lr   = row - HALFS * tile;
                int ba   = tile * XTILE + lr * XS + e;
                if (e == 100) {
                    int rowb  = row + 1;
                    int tileb = rowb >= HALFS;
                    int lrb   = rowb - HALFS * tileb;
                    *(unsigned*)(ux + ba) = xv0[it];
                    *(unsigned*)(ux + tileb * XTILE + lrb * XS) = xv1[it];
                } else {
                    uint2 t2; t2.x = xv0[it]; t2.y = xv1[it];
                    *(uint2*)(ux + ba) = t2;
                }
            }
        }
    };

    loadx(blockIdx.x);
    const int stride = (int)gridDim.x;

    #pragma unroll 1
    for (int p = blockIdx.x; p < B; p += stride) {
        stagex();
        __syncthreads();                 // bar A: x staged (+ pads, first iter)

        // ---- y-GEMM: y = x @ G, both halves, once per batch ----
        {
            bf16x8 am[2][4];
            bf16x8 zz = {};
            #pragma unroll
            for (int mi2 = 0; mi2 < 2; ++mi2) {
                const int mt = w + 4 * mi2;
                #pragma unroll
                for (int kk = 0; kk < 4; ++kk)
                    am[mi2][kk] = (mt < 7) ? *(const bf16x8*)(Mt + (16 * mt + r) * MTS + 32 * kk + 8 * g) : zz;
            }
            #pragma unroll
            for (int stl = 0; stl < 8; ++stl) {
                const short* xb = ux + (stl >> 2) * XTILE + (16 * (stl & 3) + r) * XS;
                bf16x8 bx[4];
                #pragma unroll
                for (int kk = 0; kk < 3; ++kk) bx[kk] = *(const bf16x8*)(xb + 32 * kk + 8 * g);
                bx[3] = zz;
                if (g == 0) bx[3] = *(const bf16x8*)(xb + 96);
                #pragma unroll
                for (int mi2 = 0; mi2 < 2; ++mi2) {
                    const int mt = w + 4 * mi2;
                    if (mt < 7) {
                        f32x4 acc = {0.f, 0.f, 0.f, 0.f};
                        #pragma unroll
                        for (int kk = 0; kk < 4; ++kk)
                            acc = __builtin_amdgcn_mfma_f32_16x16x32_bf16(am[mi2][kk], bx[kk], acc, 0, 0, 0);
                        if (mt < 6 || g < 2) {
                            uint2 t2; t2.x = pk2(acc[0], acc[1]); t2.y = pk2(acc[2], acc[3]);
                            *(uint2*)(uy + (stl >> 2) * XTILE + (16 * (stl & 3) + r) * XS + 16 * mt + 4 * g) = t2;
                        }
                    }
                }
            }
        }
        __syncthreads();                 // bar B: y visible

        if (p + stride < B) loadx(p + stride);   // HBM latency spans both halves

        #pragma unroll
        for (int half = 0; half < 2; ++half) {
            const short* xo = ux + (half ^ 1) * XTILE;   // keys/values rows
            const short* yo = uy + half * XTILE;         // own-half y rows

            // ---- hoist x_oth A-frags (shared by scores AND v-GEMM) ----
            bf16x8 ax[4][4];
            bf16x8 zz = {};
            #pragma unroll
            for (int mt = 0; mt < 4; ++mt) {
                const short* xb = xo + (16 * mt + r) * XS;
                #pragma unroll
                for (int kk = 0; kk < 3; ++kk) ax[mt][kk] = *(const bf16x8*)(xb + 32 * kk + 8 * g);
                ax[mt][3] = zz;
                if (g == 0) ax[mt][3] = *(const bf16x8*)(xb + 96);
            }

            const int src0 = ((g & 1) << 5) + r;
            const int src1 = src0 + 16;
            const bool hi  = (g >> 1) != 0;

            // ---- scoresT + softmax + P-exchange, per s-tile c (all waves, all c) ----
            bf16x8 bpA[4], bpB[4];
            #pragma unroll
            for (int c = 0; c < 4; ++c) {
                const short* yb = yo + (16 * c + r) * XS;
                bf16x8 by[4];
                #pragma unroll
                for (int kk = 0; kk < 3; ++kk) by[kk] = *(const bf16x8*)(yb + 32 * kk + 8 * g);
                by[3] = zz;
                if (g == 0) by[3] = *(const bf16x8*)(yb + 96);

                float sc[4][4];
                #pragma unroll
                for (int mt = 0; mt < 4; ++mt) {
                    f32x4 acc = {0.f, 0.f, 0.f, 0.f};
                    #pragma unroll
                    for (int kk = 0; kk < 4; ++kk)
                        acc = __builtin_amdgcn_mfma_f32_16x16x32_bf16(ax[mt][kk], by[kk], acc, 0, 0, 0);
                    #pragma unroll
                    for (int j = 0; j < 4; ++j) sc[mt][j] = acc[j];
                }
                #pragma unroll
                for (int j = 0; j < 4; ++j)
                    if (48 + 4 * g + j >= HALFS) sc[3][j] = -1e30f;

                float mx = -1e30f;
                #pragma unroll
                for (int mt = 0; mt < 4; ++mt) {
                    #pragma unroll
                    for (int j = 0; j < 4; ++j) mx = fmaxf(mx, sc[mt][j]);
                }
                mx = fmaxf(mx, __shfl_xor(mx, 16));
                mx = fmaxf(mx, __shfl_xor(mx, 32));
                float pr[4][4];
                float sum = 0.f;
                #pragma unroll
                for (int mt = 0; mt < 4; ++mt) {
                    #pragma unroll
                    for (int j = 0; j < 4; ++j) { pr[mt][j] = __expf(sc[mt][j] - mx); sum += pr[mt][j]; }
                }
                sum += __shfl_xor(sum, 16);
                sum += __shfl_xor(sum, 32);
                float rs = 1.0f / sum;

                unsigned pu[4][2];
                #pragma unroll
                for (int mt = 0; mt < 4; ++mt) {
                    pu[mt][0] = pk2(pr[mt][0] * rs, pr[mt][1] * rs);
                    pu[mt][1] = pk2(pr[mt][2] * rs, pr[mt][3] * rs);
                }
                // P exchange (verified in R4/R5): bpA = P[s=16c+r][t=8g..8g+7], bpB = +32
                unsigned A00 = (unsigned)__shfl((int)pu[0][0], src0), A01 = (unsigned)__shfl((int)pu[0][1], src0);
                unsigned A02 = (unsigned)__shfl((int)pu[0][0], src1), A03 = (unsigned)__shfl((int)pu[0][1], src1);
                unsigned B00 = (unsigned)__shfl((int)pu[1][0], src0), B01 = (unsigned)__shfl((int)pu[1][1], src0);
                unsigned B02 = (unsigned)__shfl((int)pu[1][0], src1), B03 = (unsigned)__shfl((int)pu[1][1], src1);
                unsigned C00 = (unsigned)__shfl((int)pu[2][0], src0), C01 = (unsigned)__shfl((int)pu[2][1], src0);
                unsigned C02 = (unsigned)__shfl((int)pu[2][0], src1), C03 = (unsigned)__shfl((int)pu[2][1], src1);
                unsigned D00 = (unsigned)__shfl((int)pu[3][0], src0), D01 = (unsigned)__shfl((int)pu[3][1], src0);
                unsigned D02 = (unsigned)__shfl((int)pu[3][0], src1), D03 = (unsigned)__shfl((int)pu[3][1], src1);
                uint4 q0, q1;
                q0.x = hi ? B00 : A00; q0.y = hi ? B01 : A01; q0.z = hi ? B02 : A02; q0.w = hi ? B03 : A03;
                q1.x = hi ? D00 : C00; q1.y = hi ? D01 : C01; q1.z = hi ? D02 : C02; q1.w = hi ? D03 : C03;
                __builtin_memcpy(&bpA[c], &q0, 16);
                __builtin_memcpy(&bpB[c], &q1, 16);
            }

            // ---- v-GEMM (reuses ax; no LDS access at all) ----
            unsigned vpk[4][3][2];
            #pragma unroll
            for (int st = 0; st < 4; ++st) {
                #pragma unroll
                for (int mi = 0; mi < 3; ++mi) {
                    f32x4 acc = {0.f, 0.f, 0.f, 0.f};
                    #pragma unroll
                    for (int kk = 0; kk < 4; ++kk)
                        acc = __builtin_amdgcn_mfma_f32_16x16x32_bf16(ax[st][kk], wvf[mi][kk], acc, 0, 0, 0);
                    vpk[st][mi][0] = pk2(acc[0], acc[1]);
                    vpk[st][mi][1] = pk2(acc[2], acc[3]);
                }
            }

            // ---- v-exchange (intra-wave) + PV + stores ----
            const size_t obase = (size_t)p * (SEQ * HEAD) + (size_t)(half * HALFS) * HEAD;
            #pragma unroll
            for (int mi = 0; mi < 3; ++mi) {
                // va0: A[row=r][t=8g..8g+7] = v[t][h=16(w+4mi)+r], t in 0..31 (st 0/1)
                unsigned e00 = (unsigned)__shfl((int)vpk[0][mi][0], src0), e01 = (unsigned)__shfl((int)vpk[0][mi][1], src0);
                unsigned e02 = (unsigned)__shfl((int)vpk[0][mi][0], src1), e03 = (unsigned)__shfl((int)vpk[0][mi][1], src1);
                unsigned f00 = (unsigned)__shfl((int)vpk[1][mi][0], src0), f01 = (unsigned)__shfl((int)vpk[1][mi][1], src0);
                unsigned f02 = (unsigned)__shfl((int)vpk[1][mi][0], src1), f03 = (unsigned)__shfl((int)vpk[1][mi][1], src1);
                uint4 u0;
                u0.x = hi ? f00 : e00; u0.y = hi ? f01 : e01; u0.z = hi ? f02 : e02; u0.w = hi ? f03 : e03;
                // va1: t in 32..63 (st 2/3)
                unsigned e10 = (unsigned)__shfl((int)vpk[2][mi][0], src0), e11 = (unsigned)__shfl((int)vpk[2][mi][1], src0);
                unsigned e12 = (unsigned)__shfl((int)vpk[2][mi][0], src1), e13 = (unsigned)__shfl((int)vpk[2][mi][1], src1);
                unsigned f10 = (unsigned)__shfl((int)vpk[3][mi][0], src0), f11 = (unsigned)__shfl((int)vpk[3][mi][1], src0);
                unsigned f12 = (unsigned)__shfl((int)vpk[3][mi][0], src1), f13 = (unsigned)__shfl((int)vpk[3][mi][1], src1);
                uint4 u1;
                u1.x = hi ? f10 : e10; u1.y = hi ? f11 : e11; u1.z = hi ? f12 : e12; u1.w = hi ? f13 : e13;
                bf16x8 va0, va1;
                __builtin_memcpy(&va0, &u0, 16);
                __builtin_memcpy(&va1, &u1, 16);

                #pragma unroll
                for (int c = 0; c < 4; ++c) {
                    f32x4 acc = {0.f, 0.f, 0.f, 0.f};
                    acc = __builtin_amdgcn_mfma_f32_16x16x32_bf16(va0, bpA[c], acc, 0, 0, 0);
                    acc = __builtin_amdgcn_mfma_f32_16x16x32_bf16(va1, bpB[c], acc, 0, 0, 0);
                    const int srow = 16 * c + r;
                    if (srow < HALFS) {
                        float4 st4; st4.x = acc[0]; st4.y = acc[1]; st4.z = acc[2]; st4.w = acc[3];
                        *(float4*)(out + obase + (size_t)srow * HEAD + 16 * (w + 4 * mi) + 4 * g) = st4;
                    }
                }
            }
        }
        __syncthreads();                 // bar C: all ux/uy reads done before restage
    }
}

extern "C" void kernel_launch(void* const* d_in, const int* in_sizes, int n_in,
                              void* d_out, int out_size, void* d_ws, size_t ws_size,
                              hipStream_t stream) {
    const float* x  = (const float*)d_in[0];
    const float* Wq = (const float*)d_in[1];
    const float* Wk = (const float*)d_in[2];
    const float* Wv = (const float*)d_in[3];
    short* ws = (short*)d_ws;                       // needs (14336+24576)*2 = 77824 B
    int B = in_sizes[0] / (SEQ * EMB);              // 8192
    int prep_elems = MT_SHORTS + HEAD * WES;
    prep<<<(prep_elems + 255) / 256, 256, 0, stream>>>(Wq, Wk, Wv, ws);
    attn_head<<<512, 256, 0, stream>>>(x, ws, (float*)d_out, B);
}